// Round 11
// baseline (1090.071 us; speedup 1.0000x reference)
//
#include <hip/hip_runtime.h>

typedef _Float16 f16;
typedef _Float16 f16x2 __attribute__((ext_vector_type(2)));
typedef _Float16 f16x4 __attribute__((ext_vector_type(4)));
typedef _Float16 f16x8 __attribute__((ext_vector_type(8)));
typedef float    f32x4 __attribute__((ext_vector_type(4)));
typedef int      intx4 __attribute__((ext_vector_type(4)));

__device__ __forceinline__ int sdot4(int a, int b, int c) {
#if __has_builtin(__builtin_amdgcn_sdot4)
  return __builtin_amdgcn_sdot4(a, b, c, false);
#else
#pragma unroll
  for (int i = 0; i < 4; ++i)
    c += ((a << (24 - 8 * i)) >> 24) * ((b << (24 - 8 * i)) >> 24);
  return c;
#endif
}

// ---------------- small helper kernels ----------------

__global__ void cvt_f32_to_f16(const float* __restrict__ in, f16* __restrict__ out, int n) {
  int i = (blockIdx.x * blockDim.x + threadIdx.x) * 4;
  if (i + 3 < n) {
    float4 v = *(const float4*)(in + i);
    f16x4 h; h[0] = (f16)v.x; h[1] = (f16)v.y; h[2] = (f16)v.z; h[3] = (f16)v.w;
    *(f16x4*)(out + i) = h;
  }
}

__global__ void bias_comb_kernel(const float* __restrict__ a, const float* __restrict__ b,
                                 float* __restrict__ o, int n) {
  int i = blockIdx.x * blockDim.x + threadIdx.x;
  if (i < n) o[i] = a[i] + b[i];
}

__global__ void zero_u32_kernel(unsigned* p) { *p = 0u; }

// abs-max of W into *out (uint-ordered float bits; all values >= 0)
__global__ void wabsmax_kernel(const float* __restrict__ in, int n, unsigned* out) {
  float m = 0.f;
  for (int i = blockIdx.x * blockDim.x + threadIdx.x; i < n; i += gridDim.x * blockDim.x)
    m = fmaxf(m, fabsf(in[i]));
#pragma unroll
  for (int off = 32; off >= 1; off >>= 1)
    m = fmaxf(m, __shfl_xor(m, off));
  if ((threadIdx.x & 63) == 0) atomicMax(out, __float_as_uint(m));
}

// quantize W to i8 with scale s = wmax/127
__global__ void quant_w_kernel(const float* __restrict__ W, signed char* __restrict__ out,
                               const unsigned* __restrict__ wmax, int n) {
  float mx = __uint_as_float(*wmax);
  float inv = mx > 0.f ? 127.f / mx : 0.f;
  int i = (blockIdx.x * blockDim.x + threadIdx.x) * 4;
  if (i + 3 < n) {
    float4 v = *(const float4*)(W + i);
    int q0 = (int)__builtin_rintf(v.x * inv);
    int q1 = (int)__builtin_rintf(v.y * inv);
    int q2 = (int)__builtin_rintf(v.z * inv);
    int q3 = (int)__builtin_rintf(v.w * inv);
    unsigned p = (unsigned)(q0 & 255) | ((unsigned)(q1 & 255) << 8) |
                 ((unsigned)(q2 & 255) << 16) | ((unsigned)(q3 & 255) << 24);
    *(unsigned*)(out + i) = p;
  }
}

// ---------------- GEMM: C[M,N] = A[M,K] * B[N,K]^T + bias[N] ----------------

#define BM 128
#define BN 128
#define BKT 32
#define LDK 40  // padded leading dim (f16 elems) to dodge bank conflicts

template <bool A_IS_F32>
__global__ __launch_bounds__(256, 2) void gemm_f16_kernel(
    const void* __restrict__ Aptr,    // [M][K]
    const f16* __restrict__ B,        // [N][K]
    const float* __restrict__ bias,   // [N]
    float* __restrict__ C,            // [M][N]
    int M, int N, int K) {
  __shared__ f16 As[BM][LDK];
  __shared__ f16 Bs[BN][LDK];

  const int tid = threadIdx.x;
  const int bm = blockIdx.y, bn = blockIdx.x;
  const int wave = tid >> 6, lane = tid & 63;
  const int wm = wave >> 1, wn = wave & 1;

  f32x4 acc[4][4] = {};

  for (int k0 = 0; k0 < K; k0 += BKT) {
#pragma unroll
    for (int it = 0; it < 2; ++it) {
      int idx = tid + it * 256;          // 0..511
      int row = idx >> 2;                // 0..127
      int kc  = (idx & 3) << 3;          // 0,8,16,24
      if (A_IS_F32) {
        const float* Af = (const float*)Aptr + (size_t)(bm * BM + row) * K + k0 + kc;
        float4 v0 = *(const float4*)Af;
        float4 v1 = *(const float4*)(Af + 4);
        f16x8 h;
        h[0] = (f16)v0.x; h[1] = (f16)v0.y; h[2] = (f16)v0.z; h[3] = (f16)v0.w;
        h[4] = (f16)v1.x; h[5] = (f16)v1.y; h[6] = (f16)v1.z; h[7] = (f16)v1.w;
        *(f16x8*)&As[row][kc] = h;
      } else {
        const f16* Ah = (const f16*)Aptr + (size_t)(bm * BM + row) * K + k0 + kc;
        *(f16x8*)&As[row][kc] = *(const f16x8*)Ah;
      }
      const f16* Bh = B + (size_t)(bn * BN + row) * K + k0 + kc;
      *(f16x8*)&Bs[row][kc] = *(const f16x8*)Bh;
    }
    __syncthreads();

    const int fr = lane & 15;
    const int fk = (lane >> 4) << 3;  // 0,8,16,24
    f16x8 af[4], bf[4];
#pragma unroll
    for (int i = 0; i < 4; ++i) af[i] = *(const f16x8*)&As[wm * 64 + i * 16 + fr][fk];
#pragma unroll
    for (int j = 0; j < 4; ++j) bf[j] = *(const f16x8*)&Bs[wn * 64 + j * 16 + fr][fk];
#pragma unroll
    for (int i = 0; i < 4; ++i)
#pragma unroll
      for (int j = 0; j < 4; ++j)
        acc[i][j] = __builtin_amdgcn_mfma_f32_16x16x32_f16(af[i], bf[j], acc[i][j], 0, 0, 0);
    __syncthreads();
  }

  const int fr = lane & 15;
  const int fq = lane >> 4;
#pragma unroll
  for (int i = 0; i < 4; ++i)
#pragma unroll
    for (int j = 0; j < 4; ++j)
#pragma unroll
      for (int r = 0; r < 4; ++r) {
        int row = bm * BM + wm * 64 + i * 16 + fq * 4 + r;
        int col = bn * BN + wn * 64 + j * 16 + fr;
        C[(size_t)row * N + col] = acc[i][j][r] + bias[col];
      }
}

// ---------------- recurrent scan (int8, in-loop register-pinned W) ----------------
// One block (512 thr, 8 waves) per batch row; thread tid owns output tid.
// W row = 32 NAMED intx4 (128 dwords i8). THE fix after rounds 1-10: the pin
// asm ("+v" on all 32) sits INSIDE the t-loop, so all 128 dwords must be
// simultaneously register-resident EVERY iteration -> spilling between pin(t)
// and use(t) buys the allocator nothing, so W stays in VGPRs.
// h feed: 2-bank group pipeline (HA/HB, 8 chunks = 8 ds_read_b128 in flight,
// consumed one group later => ~128 dot4-cycles covers the ~120cyc LDS latency),
// sched_barrier(0) per group caps peak pressure at ~128(W)+64(h)+~25 < 256.
// Integer math identical to round 7 (exact adds) -> absmax unchanged.

#define RT 512

#define PIN4(a, b, c, d) asm volatile("" : "+v"(a), "+v"(b), "+v"(c), "+v"(d));
#define DOTC(W, H)                                           \
  a0 = sdot4(W.x, H.x, a0); a1 = sdot4(W.y, H.y, a1);        \
  a2 = sdot4(W.z, H.z, a2); a3 = sdot4(W.w, H.w, a3);

__global__ __launch_bounds__(RT, 1) void rnn_scan_kernel(
    const signed char* __restrict__ Whq,  // [512][512] i8
    const unsigned* __restrict__ wmax,    // scale source
    const float* __restrict__ h0,         // [B][512] f32
    const float* __restrict__ xp,         // [B][T][512] f32 (pre-act incl. biases)
    f16* __restrict__ hs,                 // [B][T][512] f16 (out, for y-GEMM)
    float* __restrict__ hn,               // [B][512] f32 (out)
    int T) {
  __shared__ __align__(16) signed char hbuf[2][RT];   // 1 KB
  const int tid = threadIdx.x;
  const int b   = blockIdx.x;

  // combined dequant scale: value = acc_int * (wmax/127) * (1/127)
  const float qs = __uint_as_float(*wmax) * (1.0f / 16129.0f);

  // W row tid: 128 dwords of packed i8 as 32 NAMED intx4 (SSA)
  const intx4* wr = (const intx4*)(Whq + (size_t)tid * 512);
  intx4 W0 =wr[0],  W1 =wr[1],  W2 =wr[2],  W3 =wr[3],
        W4 =wr[4],  W5 =wr[5],  W6 =wr[6],  W7 =wr[7],
        W8 =wr[8],  W9 =wr[9],  W10=wr[10], W11=wr[11],
        W12=wr[12], W13=wr[13], W14=wr[14], W15=wr[15],
        W16=wr[16], W17=wr[17], W18=wr[18], W19=wr[19],
        W20=wr[20], W21=wr[21], W22=wr[22], W23=wr[23],
        W24=wr[24], W25=wr[25], W26=wr[26], W27=wr[27],
        W28=wr[28], W29=wr[29], W30=wr[30], W31=wr[31];

  {
    float hv = h0[(size_t)b * 512 + tid];
    hv = fminf(1.f, fmaxf(-1.f, hv));
    hbuf[0][tid] = (signed char)(int)__builtin_rintf(127.f * hv);
  }
  __syncthreads();

  const float* xpb = xp + (size_t)b * T * 512 + tid;
  f16* hsb = hs + (size_t)b * T * 512 + tid;

  int cur = 0;
  float hlast = 0.f;
  float xv = xpb[0];
  for (int t = 0; t < T; ++t) {
    // pin: all 32 W quads must be live in registers HERE, every iteration
    PIN4(W0, W1, W2, W3)    PIN4(W4, W5, W6, W7)
    PIN4(W8, W9, W10, W11)  PIN4(W12, W13, W14, W15)
    PIN4(W16, W17, W18, W19) PIN4(W20, W21, W22, W23)
    PIN4(W24, W25, W26, W27) PIN4(W28, W29, W30, W31)

    int tn = t + 1 < T ? t + 1 : t;
    float xn = xpb[(size_t)tn * 512];   // prefetch next step's xp

    const intx4* bcp = (const intx4*)hbuf[cur];
    int a0 = 0, a1 = 0, a2 = 0, a3 = 0;

    // group pipeline: load 8 chunks ahead (HA/HB banks)
    intx4 HA0=bcp[0], HA1=bcp[1], HA2=bcp[2], HA3=bcp[3],
          HA4=bcp[4], HA5=bcp[5], HA6=bcp[6], HA7=bcp[7];
    intx4 HB0=bcp[8], HB1=bcp[9], HB2=bcp[10], HB3=bcp[11],
          HB4=bcp[12], HB5=bcp[13], HB6=bcp[14], HB7=bcp[15];
    DOTC(W0, HA0) DOTC(W1, HA1) DOTC(W2, HA2) DOTC(W3, HA3)
    DOTC(W4, HA4) DOTC(W5, HA5) DOTC(W6, HA6) DOTC(W7, HA7)
    __builtin_amdgcn_sched_barrier(0);

    HA0=bcp[16]; HA1=bcp[17]; HA2=bcp[18]; HA3=bcp[19];
    HA4=bcp[20]; HA5=bcp[21]; HA6=bcp[22]; HA7=bcp[23];
    DOTC(W8, HB0) DOTC(W9, HB1) DOTC(W10, HB2) DOTC(W11, HB3)
    DOTC(W12, HB4) DOTC(W13, HB5) DOTC(W14, HB6) DOTC(W15, HB7)
    __builtin_amdgcn_sched_barrier(0);

    HB0=bcp[24]; HB1=bcp[25]; HB2=bcp[26]; HB3=bcp[27];
    HB4=bcp[28]; HB5=bcp[29]; HB6=bcp[30]; HB7=bcp[31];
    DOTC(W16, HA0) DOTC(W17, HA1) DOTC(W18, HA2) DOTC(W19, HA3)
    DOTC(W20, HA4) DOTC(W21, HA5) DOTC(W22, HA6) DOTC(W23, HA7)
    __builtin_amdgcn_sched_barrier(0);

    DOTC(W24, HB0) DOTC(W25, HB1) DOTC(W26, HB2) DOTC(W27, HB3)
    DOTC(W28, HB4) DOTC(W29, HB5) DOTC(W30, HB6) DOTC(W31, HB7)

    float acc = (float)((a0 + a1) + (a2 + a3)) * qs + xv;
    // tanh(x) = 1 - 2/(exp(2x)+1); branch-free
    float e = __expf(2.0f * acc);
    float hnew = 1.0f - 2.0f * __builtin_amdgcn_rcpf(e + 1.0f);
    hlast = hnew;
    hsb[(size_t)t * 512] = (f16)hnew;
    hbuf[cur ^ 1][tid] = (signed char)(int)__builtin_rintf(127.f * hnew);
    __syncthreads();
    cur ^= 1;
    xv = xn;
  }
  hn[(size_t)b * 512 + tid] = hlast;
}

// ---------------- launch ----------------

extern "C" void kernel_launch(void* const* d_in, const int* in_sizes, int n_in,
                              void* d_out, int out_size, void* d_ws, size_t ws_size,
                              hipStream_t stream) {
  const float* x    = (const float*)d_in[0];
  const float* h0   = (const float*)d_in[1];
  const float* W_xh = (const float*)d_in[2];
  const float* b_xh = (const float*)d_in[3];
  const float* W_hh = (const float*)d_in[4];
  const float* b_hh = (const float*)d_in[5];
  const float* W_hy = (const float*)d_in[6];
  const float* b_hy = (const float*)d_in[7];

  const int H = 512;
  const int B = in_sizes[1] / H;            // 64
  const int T = in_sizes[0] / (B * H);      // 1024
  const int M = B * T;                      // 65536

  float* out = (float*)d_out;               // y [M][512] then h_n [B][512]
  float* xpb = out;                         // reuse y region as xp scratch
  float* hn  = out + (size_t)M * H;

  char* w = (char*)d_ws;
  f16*         hsb    = (f16*)w;                              // M*H*2 bytes
  f16*         Wxh_h  = (f16*)(w + (size_t)M * H * 2);        // H*H f16
  f16*         Why_h  = Wxh_h + H * H;                        // H*H f16
  signed char* Whq    = (signed char*)(Why_h + H * H);        // H*H i8
  float*       biasc  = (float*)(Whq + H * H);                // H f32
  unsigned*    wmax   = (unsigned*)(biasc + H);               // 1 u32

  const int WN = H * H;  // 262144
  cvt_f32_to_f16<<<WN / 1024, 256, 0, stream>>>(W_xh, Wxh_h, WN);
  cvt_f32_to_f16<<<WN / 1024, 256, 0, stream>>>(W_hy, Why_h, WN);
  bias_comb_kernel<<<2, 256, 0, stream>>>(b_xh, b_hh, biasc, H);

  // quantize W_hh to i8 with measured absmax scale
  zero_u32_kernel<<<1, 1, 0, stream>>>(wmax);
  wabsmax_kernel<<<64, 256, 0, stream>>>(W_hh, WN, wmax);
  quant_w_kernel<<<WN / 1024, 256, 0, stream>>>(W_hh, Whq, wmax, WN);

  // xp = x @ W_xh^T + (b_xh + b_hh)   (written into d_out)
  gemm_f16_kernel<true><<<dim3(H / BN, M / BM), 256, 0, stream>>>(
      x, Wxh_h, biasc, xpb, M, H, H);

  // sequential scan; writes hs (f16, ws) and h_n (f32, d_out tail)
  rnn_scan_kernel<<<B, RT, 0, stream>>>(Whq, wmax, h0, xpb, hsb, hn, T);

  // y = hs @ W_hy^T + b_hy   (overwrites xp region of d_out)
  gemm_f16_kernel<false><<<dim3(H / BN, M / BM), 256, 0, stream>>>(
      hsb, Why_h, b_hy, out, M, H, H);
}

// Round 12
// 1008.512 us; speedup vs baseline: 1.0809x; 1.0809x over previous
//
#include <hip/hip_runtime.h>

typedef _Float16 f16;
typedef _Float16 f16x2 __attribute__((ext_vector_type(2)));
typedef _Float16 f16x4 __attribute__((ext_vector_type(4)));
typedef _Float16 f16x8 __attribute__((ext_vector_type(8)));
typedef float    f32x4 __attribute__((ext_vector_type(4)));
typedef int      intx4 __attribute__((ext_vector_type(4)));

// ---------------- small helper kernels ----------------

__global__ void cvt_f32_to_f16(const float* __restrict__ in, f16* __restrict__ out, int n) {
  int i = (blockIdx.x * blockDim.x + threadIdx.x) * 4;
  if (i + 3 < n) {
    float4 v = *(const float4*)(in + i);
    f16x4 h; h[0] = (f16)v.x; h[1] = (f16)v.y; h[2] = (f16)v.z; h[3] = (f16)v.w;
    *(f16x4*)(out + i) = h;
  }
}

__global__ void bias_comb_kernel(const float* __restrict__ a, const float* __restrict__ b,
                                 float* __restrict__ o, int n) {
  int i = blockIdx.x * blockDim.x + threadIdx.x;
  if (i < n) o[i] = a[i] + b[i];
}

__global__ void zero_u32_kernel(unsigned* p) { *p = 0u; }

// abs-max of W into *out (uint-ordered float bits; all values >= 0)
__global__ void wabsmax_kernel(const float* __restrict__ in, int n, unsigned* out) {
  float m = 0.f;
  for (int i = blockIdx.x * blockDim.x + threadIdx.x; i < n; i += gridDim.x * blockDim.x)
    m = fmaxf(m, fabsf(in[i]));
#pragma unroll
  for (int off = 32; off >= 1; off >>= 1)
    m = fmaxf(m, __shfl_xor(m, off));
  if ((threadIdx.x & 63) == 0) atomicMax(out, __float_as_uint(m));
}

// quantize W to i8 with scale s = wmax/127
__global__ void quant_w_kernel(const float* __restrict__ W, signed char* __restrict__ out,
                               const unsigned* __restrict__ wmax, int n) {
  float mx = __uint_as_float(*wmax);
  float inv = mx > 0.f ? 127.f / mx : 0.f;
  int i = (blockIdx.x * blockDim.x + threadIdx.x) * 4;
  if (i + 3 < n) {
    float4 v = *(const float4*)(W + i);
    int q0 = (int)__builtin_rintf(v.x * inv);
    int q1 = (int)__builtin_rintf(v.y * inv);
    int q2 = (int)__builtin_rintf(v.z * inv);
    int q3 = (int)__builtin_rintf(v.w * inv);
    unsigned p = (unsigned)(q0 & 255) | ((unsigned)(q1 & 255) << 8) |
                 ((unsigned)(q2 & 255) << 16) | ((unsigned)(q3 & 255) << 24);
    *(unsigned*)(out + i) = p;
  }
}

// ---------------- GEMM: C[M,N] = A[M,K] * B[N,K]^T + bias[N] ----------------

#define BM 128
#define BN 128
#define BKT 32
#define LDK 40  // padded leading dim (f16 elems) to dodge bank conflicts

template <bool A_IS_F32>
__global__ __launch_bounds__(256, 2) void gemm_f16_kernel(
    const void* __restrict__ Aptr,    // [M][K]
    const f16* __restrict__ B,        // [N][K]
    const float* __restrict__ bias,   // [N]
    float* __restrict__ C,            // [M][N]
    int M, int N, int K) {
  __shared__ f16 As[BM][LDK];
  __shared__ f16 Bs[BN][LDK];

  const int tid = threadIdx.x;
  const int bm = blockIdx.y, bn = blockIdx.x;
  const int wave = tid >> 6, lane = tid & 63;
  const int wm = wave >> 1, wn = wave & 1;

  f32x4 acc[4][4] = {};

  for (int k0 = 0; k0 < K; k0 += BKT) {
#pragma unroll
    for (int it = 0; it < 2; ++it) {
      int idx = tid + it * 256;          // 0..511
      int row = idx >> 2;                // 0..127
      int kc  = (idx & 3) << 3;          // 0,8,16,24
      if (A_IS_F32) {
        const float* Af = (const float*)Aptr + (size_t)(bm * BM + row) * K + k0 + kc;
        float4 v0 = *(const float4*)Af;
        float4 v1 = *(const float4*)(Af + 4);
        f16x8 h;
        h[0] = (f16)v0.x; h[1] = (f16)v0.y; h[2] = (f16)v0.z; h[3] = (f16)v0.w;
        h[4] = (f16)v1.x; h[5] = (f16)v1.y; h[6] = (f16)v1.z; h[7] = (f16)v1.w;
        *(f16x8*)&As[row][kc] = h;
      } else {
        const f16* Ah = (const f16*)Aptr + (size_t)(bm * BM + row) * K + k0 + kc;
        *(f16x8*)&As[row][kc] = *(const f16x8*)Ah;
      }
      const f16* Bh = B + (size_t)(bn * BN + row) * K + k0 + kc;
      *(f16x8*)&Bs[row][kc] = *(const f16x8*)Bh;
    }
    __syncthreads();

    const int fr = lane & 15;
    const int fk = (lane >> 4) << 3;  // 0,8,16,24
    f16x8 af[4], bf[4];
#pragma unroll
    for (int i = 0; i < 4; ++i) af[i] = *(const f16x8*)&As[wm * 64 + i * 16 + fr][fk];
#pragma unroll
    for (int j = 0; j < 4; ++j) bf[j] = *(const f16x8*)&Bs[wn * 64 + j * 16 + fr][fk];
#pragma unroll
    for (int i = 0; i < 4; ++i)
#pragma unroll
      for (int j = 0; j < 4; ++j)
        acc[i][j] = __builtin_amdgcn_mfma_f32_16x16x32_f16(af[i], bf[j], acc[i][j], 0, 0, 0);
    __syncthreads();
  }

  const int fr = lane & 15;
  const int fq = lane >> 4;
#pragma unroll
  for (int i = 0; i < 4; ++i)
#pragma unroll
    for (int j = 0; j < 4; ++j)
#pragma unroll
      for (int r = 0; r < 4; ++r) {
        int row = bm * BM + wm * 64 + i * 16 + fq * 4 + r;
        int col = bn * BN + wn * 64 + j * 16 + fr;
        C[(size_t)row * N + col] = acc[i][j][r] + bias[col];
      }
}

// ---------------- recurrent scan (i8 MFMA, W as AGPR-resident B-frags) -------
// One block (512 thr, 8 waves) per batch row. Wave w owns outputs
// j = 64w + 16*nt + (lane&15), nt=0..3. Per step:
//   y = h(1x512) x W^T via v_mfma_i32_16x16x64_i8, K=512 in 8 k-steps.
// A (h, changes per step): broadcast to all 16 rows -> lane l loads h bytes
//   [64s + (l>>4)*16, +16) from LDS: uniform-per-quarter ds_read_b128.
// B (W, loop-invariant): 32 intx4 frags/lane; consumed ONLY via asm "a"
//   constraints -> MUST be AGPR-resident at every use; MFMA reads AGPRs
//   natively (no accvgpr bounce - this is the fix for rounds 1-11's spills).
// D in VGPRs (C/D "v" is valid on gfx950 unified file); row 0 of D = y, held
// by lanes 0-15 at reg 0. Masked epilogue: dequant + xp + tanh + quantize.
// Math identical to round 7 (same quant, exact int accum) -> absmax unchanged.

#define RT 512

#define MFMA(d, a, b) \
  asm("v_mfma_i32_16x16x64_i8 %0, %1, %2, %0" : "+v"(d) : "v"(a), "a"(b))

#define KSTEP(s) { intx4 av = ap[4 * (s)];       \
    MFMA(d0, av, B##s##_0);                      \
    MFMA(d1, av, B##s##_1);                      \
    MFMA(d2, av, B##s##_2);                      \
    MFMA(d3, av, B##s##_3); }

#define BLD(s, nt) (*(const intx4*)(Whq + (size_t)(jb + (nt) * 16) * 512 + (s) * 64 + qoff))

__global__ __launch_bounds__(RT, 1) void rnn_scan_kernel(
    const signed char* __restrict__ Whq,  // [512][512] i8 (row j = W_hh row j)
    const unsigned* __restrict__ wmax,    // scale source
    const float* __restrict__ h0,         // [B][512] f32
    const float* __restrict__ xp,         // [B][T][512] f32 (pre-act incl. biases)
    f16* __restrict__ hs,                 // [B][T][512] f16 (out, for y-GEMM)
    float* __restrict__ hn,               // [B][512] f32 (out)
    int T) {
  __shared__ __align__(64) signed char hbuf[2][RT];   // 1 KB
  const int tid  = threadIdx.x;
  const int lane = tid & 63;
  const int w    = tid >> 6;
  const int b    = blockIdx.x;
  const int jb   = w * 64 + (lane & 15);
  const int qoff = (lane >> 4) << 4;    // k-quarter byte offset within 64

  const float qs = __uint_as_float(*wmax) * (1.0f / 16129.0f);

  // ---- load W B-fragments (loop-invariant; live in AGPRs via asm "a") ----
  intx4 B0_0=BLD(0,0), B0_1=BLD(0,1), B0_2=BLD(0,2), B0_3=BLD(0,3);
  intx4 B1_0=BLD(1,0), B1_1=BLD(1,1), B1_2=BLD(1,2), B1_3=BLD(1,3);
  intx4 B2_0=BLD(2,0), B2_1=BLD(2,1), B2_2=BLD(2,2), B2_3=BLD(2,3);
  intx4 B3_0=BLD(3,0), B3_1=BLD(3,1), B3_2=BLD(3,2), B3_3=BLD(3,3);
  intx4 B4_0=BLD(4,0), B4_1=BLD(4,1), B4_2=BLD(4,2), B4_3=BLD(4,3);
  intx4 B5_0=BLD(5,0), B5_1=BLD(5,1), B5_2=BLD(5,2), B5_3=BLD(5,3);
  intx4 B6_0=BLD(6,0), B6_1=BLD(6,1), B6_2=BLD(6,2), B6_3=BLD(6,3);
  intx4 B7_0=BLD(7,0), B7_1=BLD(7,1), B7_2=BLD(7,2), B7_3=BLD(7,3);

  {
    float hv = h0[(size_t)b * 512 + tid];
    hv = fminf(1.f, fmaxf(-1.f, hv));
    hbuf[0][tid] = (signed char)(int)__builtin_rintf(127.f * hv);
  }
  __syncthreads();

  const float* xpb = xp + (size_t)b * T * 512 + jb;
  f16* hsb = hs + (size_t)b * T * 512 + jb;

  int cur = 0;
  float hl0 = 0.f, hl1 = 0.f, hl2 = 0.f, hl3 = 0.f;
  float x0 = xpb[0], x1 = xpb[16], x2 = xpb[32], x3 = xpb[48];

  for (int t = 0; t < T; ++t) {
    int tn = t + 1 < T ? t + 1 : t;
    size_t xo = (size_t)tn * 512;
    float n0 = xpb[xo], n1 = xpb[xo + 16], n2 = xpb[xo + 32], n3 = xpb[xo + 48];

    const intx4* ap = (const intx4*)(&hbuf[cur][0] + qoff);
    intx4 d0 = {0, 0, 0, 0}, d1 = {0, 0, 0, 0}, d2 = {0, 0, 0, 0}, d3 = {0, 0, 0, 0};
    KSTEP(0) KSTEP(1) KSTEP(2) KSTEP(3)
    KSTEP(4) KSTEP(5) KSTEP(6) KSTEP(7)
    // MFMA -> VALU read hazard cushion
    asm volatile("s_nop 7\ns_nop 7" : "+v"(d0), "+v"(d1), "+v"(d2), "+v"(d3));

    if (lane < 16) {
      float y0 = (float)d0[0] * qs + x0;
      float y1 = (float)d1[0] * qs + x1;
      float y2 = (float)d2[0] * qs + x2;
      float y3 = (float)d3[0] * qs + x3;
      // tanh(x) = 1 - 2/(exp(2x)+1)
      float e0 = __expf(2.f * y0), e1 = __expf(2.f * y1);
      float e2 = __expf(2.f * y2), e3 = __expf(2.f * y3);
      hl0 = 1.f - 2.f * __builtin_amdgcn_rcpf(e0 + 1.f);
      hl1 = 1.f - 2.f * __builtin_amdgcn_rcpf(e1 + 1.f);
      hl2 = 1.f - 2.f * __builtin_amdgcn_rcpf(e2 + 1.f);
      hl3 = 1.f - 2.f * __builtin_amdgcn_rcpf(e3 + 1.f);
      size_t ho = (size_t)t * 512;
      hsb[ho] = (f16)hl0; hsb[ho + 16] = (f16)hl1;
      hsb[ho + 32] = (f16)hl2; hsb[ho + 48] = (f16)hl3;
      signed char* hbw = hbuf[cur ^ 1];
      hbw[jb]      = (signed char)(int)__builtin_rintf(127.f * hl0);
      hbw[jb + 16] = (signed char)(int)__builtin_rintf(127.f * hl1);
      hbw[jb + 32] = (signed char)(int)__builtin_rintf(127.f * hl2);
      hbw[jb + 48] = (signed char)(int)__builtin_rintf(127.f * hl3);
    }
    __syncthreads();
    cur ^= 1;
    x0 = n0; x1 = n1; x2 = n2; x3 = n3;
  }
  if (lane < 16) {
    hn[(size_t)b * 512 + jb]      = hl0;
    hn[(size_t)b * 512 + jb + 16] = hl1;
    hn[(size_t)b * 512 + jb + 32] = hl2;
    hn[(size_t)b * 512 + jb + 48] = hl3;
  }
}

// ---------------- launch ----------------

extern "C" void kernel_launch(void* const* d_in, const int* in_sizes, int n_in,
                              void* d_out, int out_size, void* d_ws, size_t ws_size,
                              hipStream_t stream) {
  const float* x    = (const float*)d_in[0];
  const float* h0   = (const float*)d_in[1];
  const float* W_xh = (const float*)d_in[2];
  const float* b_xh = (const float*)d_in[3];
  const float* W_hh = (const float*)d_in[4];
  const float* b_hh = (const float*)d_in[5];
  const float* W_hy = (const float*)d_in[6];
  const float* b_hy = (const float*)d_in[7];

  const int H = 512;
  const int B = in_sizes[1] / H;            // 64
  const int T = in_sizes[0] / (B * H);      // 1024
  const int M = B * T;                      // 65536

  float* out = (float*)d_out;               // y [M][512] then h_n [B][512]
  float* xpb = out;                         // reuse y region as xp scratch
  float* hn  = out + (size_t)M * H;

  char* w = (char*)d_ws;
  f16*         hsb    = (f16*)w;                              // M*H*2 bytes
  f16*         Wxh_h  = (f16*)(w + (size_t)M * H * 2);        // H*H f16
  f16*         Why_h  = Wxh_h + H * H;                        // H*H f16
  signed char* Whq    = (signed char*)(Why_h + H * H);        // H*H i8
  float*       biasc  = (float*)(Whq + H * H);                // H f32
  unsigned*    wmax   = (unsigned*)(biasc + H);               // 1 u32

  const int WN = H * H;  // 262144
  cvt_f32_to_f16<<<WN / 1024, 256, 0, stream>>>(W_xh, Wxh_h, WN);
  cvt_f32_to_f16<<<WN / 1024, 256, 0, stream>>>(W_hy, Why_h, WN);
  bias_comb_kernel<<<2, 256, 0, stream>>>(b_xh, b_hh, biasc, H);

  // quantize W_hh to i8 with measured absmax scale
  zero_u32_kernel<<<1, 1, 0, stream>>>(wmax);
  wabsmax_kernel<<<64, 256, 0, stream>>>(W_hh, WN, wmax);
  quant_w_kernel<<<WN / 1024, 256, 0, stream>>>(W_hh, Whq, wmax, WN);

  // xp = x @ W_xh^T + (b_xh + b_hh)   (written into d_out)
  gemm_f16_kernel<true><<<dim3(H / BN, M / BM), 256, 0, stream>>>(
      x, Wxh_h, biasc, xpb, M, H, H);

  // sequential scan; writes hs (f16, ws) and h_n (f32, d_out tail)
  rnn_scan_kernel<<<B, RT, 0, stream>>>(Whq, wmax, h0, xpb, hsb, hn, T);

  // y = hs @ W_hy^T + b_hy   (overwrites xp region of d_out)
  gemm_f16_kernel<false><<<dim3(H / BN, M / BM), 256, 0, stream>>>(
      hsb, Why_h, b_hy, out, M, H, H);
}

// Round 14
// 939.301 us; speedup vs baseline: 1.1605x; 1.0737x over previous
//
#include <hip/hip_runtime.h>

typedef _Float16 f16;
typedef _Float16 f16x2 __attribute__((ext_vector_type(2)));
typedef _Float16 f16x4 __attribute__((ext_vector_type(4)));
typedef _Float16 f16x8 __attribute__((ext_vector_type(8)));
typedef float    f32x4 __attribute__((ext_vector_type(4)));
typedef int      intx4 __attribute__((ext_vector_type(4)));

// ---------------- small helper kernels ----------------

__global__ void cvt_f32_to_f16(const float* __restrict__ in, f16* __restrict__ out, int n) {
  int i = (blockIdx.x * blockDim.x + threadIdx.x) * 4;
  if (i + 3 < n) {
    float4 v = *(const float4*)(in + i);
    f16x4 h; h[0] = (f16)v.x; h[1] = (f16)v.y; h[2] = (f16)v.z; h[3] = (f16)v.w;
    *(f16x4*)(out + i) = h;
  }
}

__global__ void bias_comb_kernel(const float* __restrict__ a, const float* __restrict__ b,
                                 float* __restrict__ o, int n) {
  int i = blockIdx.x * blockDim.x + threadIdx.x;
  if (i < n) o[i] = a[i] + b[i];
}

__global__ void zero_u32_kernel(unsigned* p) { *p = 0u; }

// abs-max of W into *out (uint-ordered float bits; all values >= 0)
__global__ void wabsmax_kernel(const float* __restrict__ in, int n, unsigned* out) {
  float m = 0.f;
  for (int i = blockIdx.x * blockDim.x + threadIdx.x; i < n; i += gridDim.x * blockDim.x)
    m = fmaxf(m, fabsf(in[i]));
#pragma unroll
  for (int off = 32; off >= 1; off >>= 1)
    m = fmaxf(m, __shfl_xor(m, off));
  if ((threadIdx.x & 63) == 0) atomicMax(out, __float_as_uint(m));
}

// quantize W to i8 with scale s = wmax/127
__global__ void quant_w_kernel(const float* __restrict__ W, signed char* __restrict__ out,
                               const unsigned* __restrict__ wmax, int n) {
  float mx = __uint_as_float(*wmax);
  float inv = mx > 0.f ? 127.f / mx : 0.f;
  int i = (blockIdx.x * blockDim.x + threadIdx.x) * 4;
  if (i + 3 < n) {
    float4 v = *(const float4*)(W + i);
    int q0 = (int)__builtin_rintf(v.x * inv);
    int q1 = (int)__builtin_rintf(v.y * inv);
    int q2 = (int)__builtin_rintf(v.z * inv);
    int q3 = (int)__builtin_rintf(v.w * inv);
    unsigned p = (unsigned)(q0 & 255) | ((unsigned)(q1 & 255) << 8) |
                 ((unsigned)(q2 & 255) << 16) | ((unsigned)(q3 & 255) << 24);
    *(unsigned*)(out + i) = p;
  }
}

// ---------------- GEMM: C[M,N] = A[M,K] * B[N,K]^T + bias[N] ----------------

#define BM 128
#define BN 128
#define BKT 32
#define LDK 40  // padded leading dim (f16 elems) to dodge bank conflicts

template <bool A_IS_F32>
__global__ __launch_bounds__(256, 2) void gemm_f16_kernel(
    const void* __restrict__ Aptr,    // [M][K]
    const f16* __restrict__ B,        // [N][K]
    const float* __restrict__ bias,   // [N]
    float* __restrict__ C,            // [M][N]
    int M, int N, int K) {
  __shared__ f16 As[BM][LDK];
  __shared__ f16 Bs[BN][LDK];

  const int tid = threadIdx.x;
  const int bm = blockIdx.y, bn = blockIdx.x;
  const int wave = tid >> 6, lane = tid & 63;
  const int wm = wave >> 1, wn = wave & 1;

  f32x4 acc[4][4] = {};

  for (int k0 = 0; k0 < K; k0 += BKT) {
#pragma unroll
    for (int it = 0; it < 2; ++it) {
      int idx = tid + it * 256;          // 0..511
      int row = idx >> 2;                // 0..127
      int kc  = (idx & 3) << 3;          // 0,8,16,24
      if (A_IS_F32) {
        const float* Af = (const float*)Aptr + (size_t)(bm * BM + row) * K + k0 + kc;
        float4 v0 = *(const float4*)Af;
        float4 v1 = *(const float4*)(Af + 4);
        f16x8 h;
        h[0] = (f16)v0.x; h[1] = (f16)v0.y; h[2] = (f16)v0.z; h[3] = (f16)v0.w;
        h[4] = (f16)v1.x; h[5] = (f16)v1.y; h[6] = (f16)v1.z; h[7] = (f16)v1.w;
        *(f16x8*)&As[row][kc] = h;
      } else {
        const f16* Ah = (const f16*)Aptr + (size_t)(bm * BM + row) * K + k0 + kc;
        *(f16x8*)&As[row][kc] = *(const f16x8*)Ah;
      }
      const f16* Bh = B + (size_t)(bn * BN + row) * K + k0 + kc;
      *(f16x8*)&Bs[row][kc] = *(const f16x8*)Bh;
    }
    __syncthreads();

    const int fr = lane & 15;
    const int fk = (lane >> 4) << 3;  // 0,8,16,24
    f16x8 af[4], bf[4];
#pragma unroll
    for (int i = 0; i < 4; ++i) af[i] = *(const f16x8*)&As[wm * 64 + i * 16 + fr][fk];
#pragma unroll
    for (int j = 0; j < 4; ++j) bf[j] = *(const f16x8*)&Bs[wn * 64 + j * 16 + fr][fk];
#pragma unroll
    for (int i = 0; i < 4; ++i)
#pragma unroll
      for (int j = 0; j < 4; ++j)
        acc[i][j] = __builtin_amdgcn_mfma_f32_16x16x32_f16(af[i], bf[j], acc[i][j], 0, 0, 0);
    __syncthreads();
  }

  const int fr = lane & 15;
  const int fq = lane >> 4;
#pragma unroll
  for (int i = 0; i < 4; ++i)
#pragma unroll
    for (int j = 0; j < 4; ++j)
#pragma unroll
      for (int r = 0; r < 4; ++r) {
        int row = bm * BM + wm * 64 + i * 16 + fq * 4 + r;
        int col = bn * BN + wn * 64 + j * 16 + fr;
        C[(size_t)row * N + col] = acc[i][j][r] + bias[col];
      }
}

// ---------------- recurrent scan (i8 MFMA v3: r13 + sound hazard fence) -----
// One block (512 thr, 8 waves) per batch row. Wave w owns outputs
// j = 64w + 16*(lane>>4) + (lane&15) -- ONE output per lane.
// Per step: y = h(1x512) x W^T via v_mfma_i32_16x16x64_i8, 8 k-steps.
// B (W, loop-invariant) in AGPRs via asm "a" (r12-proven resident + correct).
// r13's failure (absmax 0.154): the hazard cushion only pinned e0..e3, so the
// scheduler could place the o-MFMAs after the nops / read o too early -> XDL
// RAW hazard -> stale reads. r14 fix: sched_barrier(0) after the last MFMA
// and a cushion asm pinning ALL EIGHT accumulators, 24 nop cycles.
// Integer math exact and identical to r7/r12 -> absmax must be 0.0078125.

#define RT 512

#define MFMA(d, a, b) \
  asm("v_mfma_i32_16x16x64_i8 %0, %1, %2, %0" : "+v"(d) : "v"(a), "a"(b))

#define KSTEP2(s, Aeven, Bt0, Bt1, Bt2, Bt3) { \
    MFMA(Aeven##0, A##s, Bt0);                 \
    MFMA(Aeven##1, A##s, Bt1);                 \
    MFMA(Aeven##2, A##s, Bt2);                 \
    MFMA(Aeven##3, A##s, Bt3); }

#define BLD(s, nt) (*(const intx4*)(Whq + (size_t)(jb + (nt) * 16) * 512 + (s) * 64 + qoff))

__global__ __launch_bounds__(RT, 1) void rnn_scan_kernel(
    const signed char* __restrict__ Whq,  // [512][512] i8 (row j = W_hh row j)
    const unsigned* __restrict__ wmax,    // scale source
    const float* __restrict__ h0,         // [B][512] f32
    const float* __restrict__ xp,         // [B][T][512] f32 (pre-act incl. biases)
    f16* __restrict__ hs,                 // [B][T][512] f16 (out, for y-GEMM)
    float* __restrict__ hn,               // [B][512] f32 (out)
    int T) {
  __shared__ __align__(64) signed char hbuf[2][RT];   // 1 KB
  const int tid  = threadIdx.x;
  const int lane = tid & 63;
  const int w    = tid >> 6;
  const int b    = blockIdx.x;
  const int g    = lane >> 4;           // tile group 0..3
  const int jb   = w * 64 + (lane & 15);
  const int j    = jb + g * 16;         // this lane's output index
  const int qoff = g << 4;              // k-quarter byte offset within 64

  const float qs = __uint_as_float(*wmax) * (1.0f / 16129.0f);

  // ---- load W B-fragments (loop-invariant; AGPR-resident via asm "a") ----
  intx4 B0_0=BLD(0,0), B0_1=BLD(0,1), B0_2=BLD(0,2), B0_3=BLD(0,3);
  intx4 B1_0=BLD(1,0), B1_1=BLD(1,1), B1_2=BLD(1,2), B1_3=BLD(1,3);
  intx4 B2_0=BLD(2,0), B2_1=BLD(2,1), B2_2=BLD(2,2), B2_3=BLD(2,3);
  intx4 B3_0=BLD(3,0), B3_1=BLD(3,1), B3_2=BLD(3,2), B3_3=BLD(3,3);
  intx4 B4_0=BLD(4,0), B4_1=BLD(4,1), B4_2=BLD(4,2), B4_3=BLD(4,3);
  intx4 B5_0=BLD(5,0), B5_1=BLD(5,1), B5_2=BLD(5,2), B5_3=BLD(5,3);
  intx4 B6_0=BLD(6,0), B6_1=BLD(6,1), B6_2=BLD(6,2), B6_3=BLD(6,3);
  intx4 B7_0=BLD(7,0), B7_1=BLD(7,1), B7_2=BLD(7,2), B7_3=BLD(7,3);

  {
    float hv = h0[(size_t)b * 512 + tid];
    hv = fminf(1.f, fmaxf(-1.f, hv));
    hbuf[0][tid] = (signed char)(int)__builtin_rintf(127.f * hv);
  }
  __syncthreads();

  const float* xpb = xp + (size_t)b * T * 512 + j;
  f16* hsb = hs + (size_t)b * T * 512 + j;

  int cur = 0;
  float hlast = 0.f;
  float xv = xpb[0];

  for (int t = 0; t < T; ++t) {
    int tn = t + 1 < T ? t + 1 : t;
    float xn = xpb[(size_t)tn * 512];   // prefetch next step's xp (coalesced)

    // ---- hoist all 8 A-fragment loads (latency overlaps MFMA issue) ----
    const intx4* ap = (const intx4*)(&hbuf[cur][0] + qoff);
    intx4 A0 = ap[0],  A1 = ap[4],  A2 = ap[8],  A3 = ap[12],
          A4 = ap[16], A5 = ap[20], A6 = ap[24], A7 = ap[28];

    intx4 e0 = {0,0,0,0}, e1 = {0,0,0,0}, e2 = {0,0,0,0}, e3 = {0,0,0,0};
    intx4 o0 = {0,0,0,0}, o1 = {0,0,0,0}, o2 = {0,0,0,0}, o3 = {0,0,0,0};
    // even/odd k-step accumulators -> dep-chain depth 4 instead of 8
    KSTEP2(0, e, B0_0, B0_1, B0_2, B0_3)
    KSTEP2(1, o, B1_0, B1_1, B1_2, B1_3)
    KSTEP2(2, e, B2_0, B2_1, B2_2, B2_3)
    KSTEP2(3, o, B3_0, B3_1, B3_2, B3_3)
    KSTEP2(4, e, B4_0, B4_1, B4_2, B4_3)
    KSTEP2(5, o, B5_0, B5_1, B5_2, B5_3)
    KSTEP2(6, e, B6_0, B6_1, B6_2, B6_3)
    KSTEP2(7, o, B7_0, B7_1, B7_2, B7_3)
    // nothing may migrate across this point
    __builtin_amdgcn_sched_barrier(0);
    // XDL RAW hazard cushion: pin ALL EIGHT accumulators (r13 pinned only e*)
    asm volatile("s_nop 7\ns_nop 7\ns_nop 7"
                 : "+v"(e0), "+v"(e1), "+v"(e2), "+v"(e3),
                   "+v"(o0), "+v"(o1), "+v"(o2), "+v"(o3));

    // ---- every lane: one output. All 16 D rows identical -> reg 0 valid. ----
    int s0 = e0[0] + o0[0];
    int s1 = e1[0] + o1[0];
    int s2 = e2[0] + o2[0];
    int s3 = e3[0] + o3[0];
    int slo = (g & 1) ? s1 : s0;
    int shi = (g & 1) ? s3 : s2;
    int sel = (g & 2) ? shi : slo;

    float y = (float)sel * qs + xv;
    // tanh(x) = 1 - 2/(exp(2x)+1); branch-free
    float e = __expf(2.f * y);
    float hnew = 1.f - 2.f * __builtin_amdgcn_rcpf(e + 1.f);
    hlast = hnew;
    hsb[(size_t)t * 512] = (f16)hnew;                 // 128B/wave contiguous
    hbuf[cur ^ 1][j] = (signed char)(int)__builtin_rintf(127.f * hnew);
    __syncthreads();
    cur ^= 1;
    xv = xn;
  }
  hn[(size_t)b * 512 + j] = hlast;
}

// ---------------- launch ----------------

extern "C" void kernel_launch(void* const* d_in, const int* in_sizes, int n_in,
                              void* d_out, int out_size, void* d_ws, size_t ws_size,
                              hipStream_t stream) {
  const float* x    = (const float*)d_in[0];
  const float* h0   = (const float*)d_in[1];
  const float* W_xh = (const float*)d_in[2];
  const float* b_xh = (const float*)d_in[3];
  const float* W_hh = (const float*)d_in[4];
  const float* b_hh = (const float*)d_in[5];
  const float* W_hy = (const float*)d_in[6];
  const float* b_hy = (const float*)d_in[7];

  const int H = 512;
  const int B = in_sizes[1] / H;            // 64
  const int T = in_sizes[0] / (B * H);      // 1024
  const int M = B * T;                      // 65536

  float* out = (float*)d_out;               // y [M][512] then h_n [B][512]
  float* xpb = out;                         // reuse y region as xp scratch
  float* hn  = out + (size_t)M * H;

  char* w = (char*)d_ws;
  f16*         hsb    = (f16*)w;                              // M*H*2 bytes
  f16*         Wxh_h  = (f16*)(w + (size_t)M * H * 2);        // H*H f16
  f16*         Why_h  = Wxh_h + H * H;                        // H*H f16
  signed char* Whq    = (signed char*)(Why_h + H * H);        // H*H i8
  float*       biasc  = (float*)(Whq + H * H);                // H f32
  unsigned*    wmax   = (unsigned*)(biasc + H);               // 1 u32

  const int WN = H * H;  // 262144
  cvt_f32_to_f16<<<WN / 1024, 256, 0, stream>>>(W_xh, Wxh_h, WN);
  cvt_f32_to_f16<<<WN / 1024, 256, 0, stream>>>(W_hy, Why_h, WN);
  bias_comb_kernel<<<2, 256, 0, stream>>>(b_xh, b_hh, biasc, H);

  // quantize W_hh to i8 with measured absmax scale
  zero_u32_kernel<<<1, 1, 0, stream>>>(wmax);
  wabsmax_kernel<<<64, 256, 0, stream>>>(W_hh, WN, wmax);
  quant_w_kernel<<<WN / 1024, 256, 0, stream>>>(W_hh, Whq, wmax, WN);

  // xp = x @ W_xh^T + (b_xh + b_hh)   (written into d_out)
  gemm_f16_kernel<true><<<dim3(H / BN, M / BM), 256, 0, stream>>>(
      x, Wxh_h, biasc, xpb, M, H, H);

  // sequential scan; writes hs (f16, ws) and h_n (f32, d_out tail)
  rnn_scan_kernel<<<B, RT, 0, stream>>>(Whq, wmax, h0, xpb, hsb, hn, T);

  // y = hs @ W_hy^T + b_hy   (overwrites xp region of d_out)
  gemm_f16_kernel<false><<<dim3(H / BN, M / BM), 256, 0, stream>>>(
      hsb, Why_h, b_hy, out, M, H, H);
}